// Round 11
// baseline (33.014 us; speedup 1.0000x reference)
//
#include <hip/hip_runtime.h>

// APLoss (r2d2 QAPLoss). B=2, H=W=32 -> N=M=1024/batch, D=128, 25 bins.
// u = 24*(1-sim); cumsum_k of triangular bins = clamp(k+1-u, 0, 1).
// R10 structure (best: 27.9us) minus one launch: k_gs (512 blk) ->
// k_main (block = 8q x ALL 1024m, 512 thr, ping-pong dbt pipeline, scalar
// q-loads, label prefetch) with fused deterministic last-block final reduce.

#define NQB 25

// DPP butterfly add over 16-lane rows (pure VALU, no LDS pipe).
template<int CTRL>
__device__ __forceinline__ float dppadd(float v) {
    int s = __builtin_amdgcn_update_dpp(0, __float_as_int(v), CTRL, 0xf, 0xf, true);
    return v + __int_as_float(s);
}
__device__ __forceinline__ float red16(float v) {
    v = dppadd<0xB1>(v);   // quad_perm xor1
    v = dppadd<0x4E>(v);   // quad_perm xor2
    v = dppadd<0x141>(v);  // row_half_mirror = xor7
    v = dppadd<0x140>(v);  // row_mirror      = xor15
    return v;              // every lane: its 16-lane-row sum
}

// ---- K1: bilinear grid-sample desc2 -> dbt[b][c][m]; block = (b,c,half) ----
__global__ __launch_bounds__(256) void k_gs(const float* __restrict__ desc2,
                                            const float* __restrict__ grd,
                                            float* __restrict__ dbt,
                                            int* __restrict__ cnt)
{
    __shared__ float plane[1024];
    int r = blockIdx.x;            // (b*128 + c)*2 + half
    int tid = threadIdx.x;
    if (r == 0 && tid == 0) *cnt = 0;   // re-arm fused-final ticket each call
    int half = r & 1;
    int bc = r >> 1;               // b*128 + c
    int b = bc >> 7;
    const float* src = desc2 + ((size_t)bc << 10);
    *(float4*)&plane[tid * 4] = *(const float4*)&src[tid * 4];
    __syncthreads();
#pragma unroll
    for (int e = 0; e < 2; e++) {
        int m = (half << 9) + tid + (e << 8);
        int pos = (b << 10) + m;
        float2 g = ((const float2*)grd)[pos];
        float fx = ((g.x + 1.f) * 32.f - 1.f) * 0.5f;
        float fy = ((g.y + 1.f) * 32.f - 1.f) * 0.5f;
        float x0f = floorf(fx), y0f = floorf(fy);
        float wx1 = fx - x0f, wy1 = fy - y0f;
        float wx0 = 1.f - wx1, wy0 = 1.f - wy1;
        int x0 = (int)x0f, y0 = (int)y0f;
        float acc = 0.f;
        if ((unsigned)y0 < 32u && (unsigned)x0 < 32u)
            acc += wy0 * wx0 * plane[(y0 << 5) + x0];
        if ((unsigned)y0 < 32u && (unsigned)(x0 + 1) < 32u)
            acc += wy0 * wx1 * plane[(y0 << 5) + x0 + 1];
        if ((unsigned)(y0 + 1) < 32u && (unsigned)x0 < 32u)
            acc += wy1 * wx0 * plane[((y0 + 1) << 5) + x0];
        if ((unsigned)(y0 + 1) < 32u && (unsigned)(x0 + 1) < 32u)
            acc += wy1 * wx1 * plane[((y0 + 1) << 5) + x0 + 1];
        dbt[((size_t)bc << 10) + m] = acc;
    }
}

// ---- sim helpers: chunk = 8 consecutive c ----------------------------------
__device__ __forceinline__ void loadc(const float* __restrict__ dp, int ch,
                                      float* d)
{
    int cb = ch << 3;
#pragma unroll
    for (int i = 0; i < 8; i++) {
        d[i]     = dp[(size_t)(cb + i) << 10];           // m = tid
        d[8 + i] = dp[(((size_t)(cb + i)) << 10) + 512]; // m = tid + 512
    }
}
__device__ __forceinline__ void fmac(const float* __restrict__ d1, int ch,
                                     const float* d, float* a0, float* a1)
{
    int cb = ch << 3;
#pragma unroll
    for (int i = 0; i < 8; i++) {
        const float* qp = d1 + ((size_t)(cb + i) << 10);
#pragma unroll
        for (int qq = 0; qq < 8; qq++) {
            float qv = qp[qq];   // wave-uniform -> scalar load
            a0[qq] = fmaf(qv, d[i], a0[qq]);
            a1[qq] = fmaf(qv, d[8 + i], a1[qq]);
        }
    }
}

// ---- K2: fused sim + histogram + AP + last-block final reduce --------------
// block = 8 q x ALL 1024 m, 512 thr (8 waves).
__global__ __launch_bounds__(512) void k_main(const float* __restrict__ desc1,
                                              const float* __restrict__ dbt,
                                              const int* __restrict__ label,
                                              float* __restrict__ appart,
                                              int* __restrict__ cnt,
                                              float* __restrict__ out,
                                              float invn)
{
    __shared__ float s[8][1024];    // sim tile
    __shared__ float CNs[8][4][NQB];
    __shared__ float CRs[8][4][NQB];
    __shared__ float apb[8];
    __shared__ int lastflag;

    int tid = threadIdx.x;
    int qg0 = blockIdx.x << 3;      // global query base (b*1024 + n0)
    int b = qg0 >> 10;
    int n0 = qg0 & 1023;

    // ---- label prefetch (registers, static indices; hides under sim) ----
    int q = tid >> 6, l = tid & 63; // hist roles
    const int* lp = label + ((size_t)(qg0 + q) << 10) + l;
    int lv[16];
#pragma unroll
    for (int e = 0; e < 16; e++) lv[e] = lp[(size_t)(e << 6)];

    // ---- sim phase: 2-deep ping-pong pipeline over 16 chunks of 8 c ----
    const float* d1 = desc1 + ((size_t)b << 17) + n0;  // q-row: d1[(c<<10)+qq]
    const float* dp = dbt + ((size_t)b << 17) + tid;

    float a0[8], a1[8];
#pragma unroll
    for (int qq = 0; qq < 8; qq++) { a0[qq] = 0.f; a1[qq] = 0.f; }

    float dA[16], dB[16];
    loadc(dp, 0, dA);
    for (int ch = 0; ch < 16; ch += 2) {
        loadc(dp, ch + 1, dB);          // issue next chunk
        fmac(d1, ch, dA, a0, a1);       // consume current
        if (ch + 2 < 16) loadc(dp, ch + 2, dA);
        fmac(d1, ch + 1, dB, a0, a1);
    }
#pragma unroll
    for (int qq = 0; qq < 8; qq++) { s[qq][tid] = a0[qq]; s[qq][tid + 512] = a1[qq]; }
    __syncthreads();

    // ---- histogram: wave = query, lane l owns m = l + 64e (conflict-free) --
    float CN[NQB], CR[NQB];
#pragma unroll
    for (int k = 0; k < NQB; k++) { CN[k] = 0.f; CR[k] = 0.f; }
#pragma unroll
    for (int e = 0; e < 16; e++) {
        float sv = s[q][l + (e << 6)];
        float lfv = (float)lv[e];
        float u = fmaf(-24.f, sv, 24.f);
#pragma unroll
        for (int k = 0; k < NQB; k++) {
            float t = fminf(fmaxf((float)(k + 1) - u, 0.f), 1.f);  // v_med3
            CN[k] += t;
            CR[k] = fmaf(lfv, t, CR[k]);
        }
    }
#pragma unroll
    for (int k = 0; k < NQB; k++) { CN[k] = red16(CN[k]); CR[k] = red16(CR[k]); }
    if ((l & 15) == 0) {
        int rec = l >> 4;
#pragma unroll
        for (int k = 0; k < NQB; k++) { CNs[q][rec][k] = CN[k]; CRs[q][rec][k] = CR[k]; }
    }
    __syncthreads();

    // ---- AP per query (8 threads), block sum ----
    if (tid < 8) {
        float ap = 0.f, prev = 0.f;
#pragma unroll
        for (int k = 0; k < NQB; k++) {
            float cn = CNs[tid][0][k] + CNs[tid][1][k] + CNs[tid][2][k] + CNs[tid][3][k];
            float cr = CRs[tid][0][k] + CRs[tid][1][k] + CRs[tid][2][k] + CRs[tid][3][k];
            float pr = cr / (1e-16f + cn);
            ap += pr * (cr - prev);
            prev = cr;
        }
        apb[tid] = ap / prev;
    }
    __syncthreads();

    // ---- publish partial + deterministic last-block final reduce ----
    int nblk = (int)gridDim.x;
    if (tid == 0) {
        float v = apb[0] + apb[1] + apb[2] + apb[3]
                + apb[4] + apb[5] + apb[6] + apb[7];
        appart[blockIdx.x] = v;
        __threadfence();                       // release partial
        int ticket = atomicAdd(cnt, 1);        // device-scope
        lastflag = (ticket == nblk - 1);
    }
    __syncthreads();
    if (lastflag) {
        __threadfence();                       // acquire all partials
        float v = 0.f;
        for (int i = tid; i < nblk; i += 512) v += appart[i];
        for (int off = 32; off; off >>= 1) v += __shfl_xor(v, off, 64);
        __shared__ float wsum[8];
        if ((tid & 63) == 0) wsum[tid >> 6] = v;
        __syncthreads();
        if (tid == 0) {
            float t = 0.f;
#pragma unroll
            for (int i = 0; i < 8; i++) t += wsum[i];
            out[0] = t * invn;
        }
    }
}

extern "C" void kernel_launch(void* const* d_in, const int* in_sizes, int n_in,
                              void* d_out, int out_size, void* d_ws, size_t ws_size,
                              hipStream_t stream)
{
    const float* desc1 = (const float*)d_in[0];
    const float* desc2 = (const float*)d_in[1];
    // d_in[2] = reliability: unused by the reference output
    const float* grd   = (const float*)d_in[3];
    const int*   label = (const int*)d_in[4];

    int B = in_sizes[0] / (128 * 1024);
    int npos = B * 1024;
    int nblk = npos / 8;

    float* ws = (float*)d_ws;
    float* dbt    = ws;                          // npos*128 floats ([b][c][m])
    float* appart = dbt + (size_t)npos * 128;    // nblk floats
    int*   cnt    = (int*)(appart + nblk);       // 1 int (re-armed by k_gs)
    float* out = (float*)d_out;

    k_gs<<<B * 256, 256, 0, stream>>>(desc2, grd, dbt, cnt);
    k_main<<<nblk, 512, 0, stream>>>(desc1, dbt, label, appart, cnt, out,
                                     1.f / (float)npos);
}

// Round 12
// 31.037 us; speedup vs baseline: 1.0637x; 1.0637x over previous
//
#include <hip/hip_runtime.h>

// APLoss (r2d2 QAPLoss). B=2, H=W=32 -> N=M=1024/batch, D=128, 25 bins.
// u = 24*(1-sim); cumsum_k of triangular bins = clamp(k+1-u, 0, 1).
// R10 structure (best: 27.9us): k_gs -> k_main (8q x 1024m, 512thr, ping-pong
// dbt pipeline, scalar q-loads, label prefetch) -> k_final.
// R12: packed-f32 (v_pk_fma_f32) sim + hist pairs -> ~40% fewer VALU insts.

#define NQB 25

typedef float f32x2 __attribute__((ext_vector_type(2)));
__device__ __forceinline__ f32x2 pk(float x) { f32x2 v; v.x = x; v.y = x; return v; }

// DPP butterfly add over 16-lane rows (pure VALU, no LDS pipe).
template<int CTRL>
__device__ __forceinline__ float dppadd(float v) {
    int s = __builtin_amdgcn_update_dpp(0, __float_as_int(v), CTRL, 0xf, 0xf, true);
    return v + __int_as_float(s);
}
__device__ __forceinline__ float red16(float v) {
    v = dppadd<0xB1>(v);   // quad_perm xor1
    v = dppadd<0x4E>(v);   // quad_perm xor2
    v = dppadd<0x141>(v);  // row_half_mirror = xor7
    v = dppadd<0x140>(v);  // row_mirror      = xor15
    return v;              // every lane: its 16-lane-row sum
}

// ---- K1: bilinear grid-sample desc2 -> dbt[b][c][m]; block = (b,c) ---------
__global__ __launch_bounds__(256) void k_gs(const float* __restrict__ desc2,
                                            const float* __restrict__ grd,
                                            float* __restrict__ dbt)
{
    __shared__ float plane[1024];
    int r = blockIdx.x;            // b*128 + c
    int b = r >> 7;
    int tid = threadIdx.x;
    const float* src = desc2 + ((size_t)r << 10);
    *(float4*)&plane[tid * 4] = *(const float4*)&src[tid * 4];
    __syncthreads();
#pragma unroll
    for (int e = 0; e < 4; e++) {
        int m = tid + (e << 8);
        int pos = (b << 10) + m;
        float2 g = ((const float2*)grd)[pos];
        float fx = ((g.x + 1.f) * 32.f - 1.f) * 0.5f;
        float fy = ((g.y + 1.f) * 32.f - 1.f) * 0.5f;
        float x0f = floorf(fx), y0f = floorf(fy);
        float wx1 = fx - x0f, wy1 = fy - y0f;
        float wx0 = 1.f - wx1, wy0 = 1.f - wy1;
        int x0 = (int)x0f, y0 = (int)y0f;
        float acc = 0.f;
        if ((unsigned)y0 < 32u && (unsigned)x0 < 32u)
            acc += wy0 * wx0 * plane[(y0 << 5) + x0];
        if ((unsigned)y0 < 32u && (unsigned)(x0 + 1) < 32u)
            acc += wy0 * wx1 * plane[(y0 << 5) + x0 + 1];
        if ((unsigned)(y0 + 1) < 32u && (unsigned)x0 < 32u)
            acc += wy1 * wx0 * plane[((y0 + 1) << 5) + x0];
        if ((unsigned)(y0 + 1) < 32u && (unsigned)(x0 + 1) < 32u)
            acc += wy1 * wx1 * plane[((y0 + 1) << 5) + x0 + 1];
        dbt[((size_t)r << 10) + m] = acc;
    }
}

// ---- sim helpers: chunk = 8 consecutive c, packed (m, m+512) pairs ---------
__device__ __forceinline__ void loadc(const float* __restrict__ dp, int ch,
                                      f32x2* d)
{
    int cb = ch << 3;
#pragma unroll
    for (int i = 0; i < 8; i++) {
        f32x2 v;
        v.x = dp[(size_t)(cb + i) << 10];            // m = tid
        v.y = dp[(((size_t)(cb + i)) << 10) + 512];  // m = tid + 512
        d[i] = v;
    }
}
__device__ __forceinline__ void fmac(const float* __restrict__ d1, int ch,
                                     const f32x2* d, f32x2* a)
{
    int cb = ch << 3;
#pragma unroll
    for (int i = 0; i < 8; i++) {
        const float* qp = d1 + ((size_t)(cb + i) << 10);
#pragma unroll
        for (int qq = 0; qq < 8; qq++) {
            float qv = qp[qq];   // wave-uniform -> scalar load
            a[qq] = __builtin_elementwise_fma(pk(qv), d[i], a[qq]);  // v_pk_fma_f32
        }
    }
}

// ---- K2: fused sim + histogram + AP; block = 8 q x ALL 1024 m, 512 thr -----
__global__ __launch_bounds__(512) void k_main(const float* __restrict__ desc1,
                                              const float* __restrict__ dbt,
                                              const int* __restrict__ label,
                                              float* __restrict__ appart)
{
    __shared__ float s[8][1024];    // sim tile
    __shared__ float CNs[8][4][NQB];
    __shared__ float CRs[8][4][NQB];
    __shared__ float apb[8];

    int tid = threadIdx.x;
    int qg0 = blockIdx.x << 3;      // global query base (b*1024 + n0)
    int b = qg0 >> 10;
    int n0 = qg0 & 1023;

    // ---- label prefetch (registers, static indices; hides under sim) ----
    int q = tid >> 6, l = tid & 63; // hist roles
    const int* lp = label + ((size_t)(qg0 + q) << 10) + l;
    int lv[16];
#pragma unroll
    for (int e = 0; e < 16; e++) lv[e] = lp[(size_t)(e << 6)];

    // ---- sim phase: 2-deep ping-pong pipeline over 16 chunks of 8 c ----
    const float* d1 = desc1 + ((size_t)b << 17) + n0;  // q-row: d1[(c<<10)+qq]
    const float* dp = dbt + ((size_t)b << 17) + tid;

    f32x2 a[8];
#pragma unroll
    for (int qq = 0; qq < 8; qq++) a[qq] = pk(0.f);

    f32x2 dA[8], dB[8];
    loadc(dp, 0, dA);
    for (int ch = 0; ch < 16; ch += 2) {
        loadc(dp, ch + 1, dB);          // issue next chunk
        fmac(d1, ch, dA, a);            // consume current
        if (ch + 2 < 16) loadc(dp, ch + 2, dA);
        fmac(d1, ch + 1, dB, a);
    }
#pragma unroll
    for (int qq = 0; qq < 8; qq++) { s[qq][tid] = a[qq].x; s[qq][tid + 512] = a[qq].y; }
    __syncthreads();

    // ---- histogram: wave = query, lane l owns m = l + 64e; packed (e, e+8) -
    f32x2 CN2[NQB], CR2[NQB];
#pragma unroll
    for (int k = 0; k < NQB; k++) { CN2[k] = pk(0.f); CR2[k] = pk(0.f); }
#pragma unroll
    for (int e = 0; e < 8; e++) {
        f32x2 sv2, lf2;
        sv2.x = s[q][l + (e << 6)];
        sv2.y = s[q][l + ((e + 8) << 6)];
        lf2.x = (float)lv[e];
        lf2.y = (float)lv[e + 8];
        f32x2 u2 = __builtin_elementwise_fma(pk(-24.f), sv2, pk(24.f));
#pragma unroll
        for (int k = 0; k < NQB; k++) {
            f32x2 t2 = pk((float)(k + 1)) - u2;                        // v_pk_add
            t2 = __builtin_elementwise_max(t2, pk(0.f));               // v_pk_max
            t2 = __builtin_elementwise_min(t2, pk(1.f));               // v_pk_min
            CN2[k] += t2;                                              // v_pk_add
            CR2[k] = __builtin_elementwise_fma(lf2, t2, CR2[k]);       // v_pk_fma
        }
    }
    float CN[NQB], CR[NQB];
#pragma unroll
    for (int k = 0; k < NQB; k++) {
        CN[k] = red16(CN2[k].x + CN2[k].y);
        CR[k] = red16(CR2[k].x + CR2[k].y);
    }
    if ((l & 15) == 0) {
        int rec = l >> 4;
#pragma unroll
        for (int k = 0; k < NQB; k++) { CNs[q][rec][k] = CN[k]; CRs[q][rec][k] = CR[k]; }
    }
    __syncthreads();

    // ---- AP per query (8 threads), block sum -> 1 float ----
    if (tid < 8) {
        float ap = 0.f, prev = 0.f;
#pragma unroll
        for (int k = 0; k < NQB; k++) {
            float cn = CNs[tid][0][k] + CNs[tid][1][k] + CNs[tid][2][k] + CNs[tid][3][k];
            float cr = CRs[tid][0][k] + CRs[tid][1][k] + CRs[tid][2][k] + CRs[tid][3][k];
            float pr = cr / (1e-16f + cn);
            ap += pr * (cr - prev);
            prev = cr;
        }
        apb[tid] = ap / prev;
    }
    __syncthreads();
    if (tid == 0) {
        float v = 0.f;
#pragma unroll
        for (int q2 = 0; q2 < 8; q2++) v += apb[q2];
        appart[blockIdx.x] = v;
    }
}

// ---- K3: final reduce of per-block sums -> d_out ---------------------------
__global__ __launch_bounds__(256) void k_final(const float* __restrict__ appart,
                                               float* __restrict__ out,
                                               int nb, float invn)
{
    int tid = threadIdx.x;
    float v = 0.f;
    for (int i = tid; i < nb; i += 256) v += appart[i];
    for (int off = 32; off; off >>= 1) v += __shfl_xor(v, off, 64);
    __shared__ float wsum[4];
    if ((tid & 63) == 0) wsum[tid >> 6] = v;
    __syncthreads();
    if (tid == 0) out[0] = (wsum[0] + wsum[1] + wsum[2] + wsum[3]) * invn;
}

extern "C" void kernel_launch(void* const* d_in, const int* in_sizes, int n_in,
                              void* d_out, int out_size, void* d_ws, size_t ws_size,
                              hipStream_t stream)
{
    const float* desc1 = (const float*)d_in[0];
    const float* desc2 = (const float*)d_in[1];
    // d_in[2] = reliability: unused by the reference output
    const float* grd   = (const float*)d_in[3];
    const int*   label = (const int*)d_in[4];

    int B = in_sizes[0] / (128 * 1024);
    int npos = B * 1024;

    float* ws = (float*)d_ws;
    float* dbt    = ws;                          // npos*128 floats ([b][c][m])
    float* appart = dbt + (size_t)npos * 128;    // npos/8 floats
    float* out = (float*)d_out;

    k_gs<<<B * 128, 256, 0, stream>>>(desc2, grd, dbt);
    k_main<<<npos / 8, 512, 0, stream>>>(desc1, dbt, label, appart);
    k_final<<<1, 256, 0, stream>>>(appart, out, npos / 8, 1.f / (float)npos);
}